// Round 11
// baseline (329.346 us; speedup 1.0000x reference)
//
#include <hip/hip_runtime.h>
#include <stdint.h>

#define HH 96
#define WW 96
#define NN (HH*WW)
#define NW 192   // bitmap words: 96 rows x 2 (128-bit padded rows, cols 96..127 dead)

// ws layout (bytes):
//   [0,      663552)  rankp u32[18][9216]  packed (E<<16)|G partials
//   [663552, 665088)  kw    u64[192]       kept bitmap words

__device__ __forceinline__ int coord1(int a) { return (10 * a + 1) / 3; }

// Aligned shifted word: result bit b (cell col 64h+b) = src-row bit (64h+b+dj).
__device__ __forceinline__ unsigned long long shifted(unsigned long long A,
                                                      unsigned long long B,
                                                      int h, int dj) {
    const unsigned long long W0 = h ? B : A;
    if (dj == 0) return W0;
    if (dj > 0) {
        const unsigned long long Wr = h ? 0ULL : B;
        return (W0 >> dj) | (Wr << (64 - dj));
    }
    const int d = -dj;
    const unsigned long long Wl = h ? A : 0ULL;
    return (W0 << d) | (Wl >> (64 - d));
}

// One dispatch, disjoint block roles, ZERO cross-block sync (R6/R8 lesson).
// Blocks 0..161: counting-rank partials (162 blocks: R10 post-mortem showed
// kA's 43.6us is NOT the NMS block — halve per-CU rank work and cheapen the
// compare to bit-compare of nonneg floats). Block 162: bit-parallel greedy
// NMS (== lexicographically-first MIS; exact-integer iou>0.5 per R0; 2nd
// NMS pass @0.7 provably a no-op; free-running monotone fixpoint per R10).
__global__ __launch_bounds__(1024, 1) void kA(const float* __restrict__ cls,
                                              unsigned int* __restrict__ rankp,
                                              unsigned long long* __restrict__ kw) {
    __shared__ __align__(16) float s[NN];         // 36 KB (rank blocks use 2 KB)
    __shared__ unsigned long long Hh[12][NW];     // 18 KB
    __shared__ unsigned long long K[NW], D[NW];   // 3 KB
    const int tid = threadIdx.x;
    const int bid = blockIdx.x;

    if (bid < 162) {
        // ---- rank partials: (k-tile of 1024) x (m-half-tile of 512) ----
        // Scores are jax.random.uniform in [0,1): non-negative, so IEEE bits
        // compare identically to floats. Pack (equal_count<<16)|greater_count;
        // sums over 18 tiles can't carry (sum_G <= 9216 < 65536).
        const int kt = bid % 9, mh = bid / 9;
        const int base = mh * 512;
        uint4* smi = (uint4*)s;
        if (tid < 128) smi[tid] = ((const uint4*)(cls + base))[tid];
        __syncthreads();
        const int k = kt * 1024 + tid;
        const unsigned kb = __float_as_uint(cls[k]);
        unsigned acc = 0;
        #pragma unroll 4
        for (int m4 = 0; m4 < 128; ++m4) {
            const uint4 v = smi[m4];
            acc += (v.x > kb) + (v.y > kb) + (v.z > kb) + (v.w > kb);
            acc += ((unsigned)((v.x == kb) + (v.y == kb) + (v.z == kb) + (v.w == kb))) << 16;
        }
        rankp[mh * NN + k] = acc;
        return;
    }

    // ---- NMS block ----
    const int lane = tid & 63;
    const int wave = tid >> 6;
    const int offs_di[12] = {0,0, 0,0, -1,1, -2,2, -1,-1, 1,1};
    const int offs_dj[12] = {-1,1,-2,2,  0,0,  0,0, -1, 1,-1,1};
    for (int i = tid; i < NN/4; i += 1024)
        ((float4*)s)[i] = ((const float4*)cls)[i];
    __syncthreads();
    // Build H masks + K/D init via ballot. Word w: row w>>1, col base 64*(w&1);
    // lane l <-> col base+l. 16 waves x 12 iters = 192 words.
    // Geometry is constant-folded: the 21x21-box intersection>294 test reduces
    // to a (col mod 3, row mod 3) pattern per edge (coord1 diffs are 3/4 for
    // step 1 and 6/7 for step 2; edge iff step2-diff==6, diag iff not both 4).
    for (int it = 0; it < 12; ++it) {
        const int w = wave + (it << 4);
        const int row = w >> 1;
        const int col = ((w & 1) << 6) + lane;
        const bool incell = (col < WW);
        const int c = row * WW + col;
        const float sc = incell ? s[c] : 0.0f;
        const int cm3 = col % 3, rm3 = row % 3;
        const unsigned long long dinit = __ballot(!incell || !(sc > 0.6f));
        if (lane == 0) { D[w] = dinit; K[w] = 0ULL; }
        #pragma unroll
        for (int e = 0; e < 12; ++e) {
            const int ii = row + offs_di[e], jj = col + offs_dj[e];
            bool geo;
            switch (e) {
                case 2:  geo = (cm3 == 1); break;              // (0,-2)
                case 3:  geo = (cm3 == 2); break;              // (0,+2)
                case 6:  geo = (rm3 == 1); break;              // (-2,0)
                case 7:  geo = (rm3 == 2); break;              // (+2,0)
                case 8:  geo = !(cm3 == 2 && rm3 == 2); break; // (-1,-1)
                case 9:  geo = !(cm3 == 1 && rm3 == 2); break; // (-1,+1)
                case 10: geo = !(cm3 == 2 && rm3 == 1); break; // (+1,-1)
                case 11: geo = !(cm3 == 1 && rm3 == 1); break; // (+1,+1)
                default: geo = true;                           // step-1 edges
            }
            bool hp = false;
            if (incell && geo && ii >= 0 && ii < HH && jj >= 0 && jj < WW) {
                const int v = ii * WW + jj;
                const float sv = s[v];
                hp = (sv > sc) || (sv == sc && v < c);
            }
            const unsigned long long m = __ballot(hp);
            if (lane == 0) Hh[e][w] = m;
        }
    }
    __syncthreads();          // last barrier: all 16 waves present
    if (wave >= 3) return;    // waves 3..15 done; 0..2 free-run (no barriers)

    // Free-running monotone fixpoint (R10-validated): thread w owns word w.
    // Write order K-then-D, read order D-then-K: LDS applies per-wave ops in
    // order and volatile preserves program order, so D=1 observed => that
    // neighbor's K is current (no false "determined-not-kept").
    volatile unsigned long long* vK = K;
    volatile unsigned long long* vD = D;
    const int w = tid;
    const int row = w >> 1, h = w & 1;
    unsigned long long Hr[12];
    #pragma unroll
    for (int e = 0; e < 12; ++e) Hr[e] = Hh[e][w];
    unsigned long long myK = K[w], myD = D[w];    // own words: only this thread writes
    for (int iter = 0; iter < 4096; ++iter) {
        if (!~myD) break;                          // fully determined: final
        unsigned long long DA[5], DB[5], KA[5], KB[5];
        #pragma unroll
        for (int q = 0; q < 5; ++q) {              // D reads FIRST
            const int rr = row + q - 2;
            const bool ok = (rr >= 0) && (rr < HH);
            DA[q] = ok ? vD[rr*2]   : 0ULL;
            DB[q] = ok ? vD[rr*2+1] : 0ULL;        // out-of-grid: H=0 there anyway
        }
        #pragma unroll
        for (int q = 0; q < 5; ++q) {              // K reads AFTER D
            const int rr = row + q - 2;
            const bool ok = (rr >= 0) && (rr < HH);
            KA[q] = ok ? vK[rr*2]   : 0ULL;
            KB[q] = ok ? vK[rr*2+1] : 0ULL;
        }
        unsigned long long supp = 0ULL, alldet = ~0ULL;
        #pragma unroll
        for (int e = 0; e < 12; ++e) {
            const int q = offs_di[e] + 2;
            const int dj = offs_dj[e];
            supp   |=  Hr[e] & shifted(KA[q], KB[q], h, dj);
            alldet &= ~Hr[e] | shifted(DA[q], DB[q], h, dj);
        }
        const unsigned long long U = ~myD;
        myK = myK | (U & alldet & ~supp);
        myD = myD | (U & (supp | alldet));
        vK[w] = myK;                               // K write BEFORE D write
        vD[w] = myD;
    }
    kw[w] = myK;   // own word final; no cross-wave read needed
}

// Epilogue: r = rank[k] is a permutation of [0,9216) — every output row
// written exactly once (non-kept rows -> zeros, no d_out memset needed).
__global__ void kout(const float* __restrict__ score, const float* __restrict__ reg,
                     const unsigned int* __restrict__ rankp,
                     const unsigned long long* __restrict__ kw,
                     float* __restrict__ out) {
    const int k = blockIdx.x * 256 + threadIdx.x;
    unsigned sum = 0;
    #pragma unroll
    for (int y = 0; y < 18; ++y) sum += rankp[y * NN + k];
    int r = (int)(sum & 0xFFFFu);
    const unsigned E = sum >> 16;                  // equal-count incl. self
    if (E != 1u) {
        // ties in score bits (practically never): exact stable-rank rescan
        const unsigned kb = __float_as_uint(score[k]);
        r = 0;
        for (int m = 0; m < NN; ++m) {
            const unsigned mb = __float_as_uint(score[m]);
            r += (mb > kb) || (mb == kb && m < k);
        }
    }
    const int j = k % WW, i = k / WW;
    const bool kp = ((kw[i * 2 + (j >> 6)] >> (j & 63)) & 1ULL) != 0ULL;
    const float x1 = (float)coord1(j);
    const float y1 = (float)coord1(i);
    const float4 d = ((const float4*)reg)[k];
    float* o = out + (size_t)r * 5;
    o[0] = kp ? (x1 + d.x * 21.0f) : 0.0f;
    o[1] = kp ? (y1 + d.y * 21.0f) : 0.0f;
    o[2] = kp ? (x1 + 20.0f + d.z * 21.0f) : 0.0f;
    o[3] = kp ? (y1 + 20.0f + d.w * 21.0f) : 0.0f;
    o[4] = kp ? score[k] : 0.0f;
}

extern "C" void kernel_launch(void* const* d_in, const int* in_sizes, int n_in,
                              void* d_out, int out_size, void* d_ws, size_t ws_size,
                              hipStream_t stream) {
    const float* cls = (const float*)d_in[0];
    const float* reg = (const float*)d_in[1];
    float* out = (float*)d_out;
    char* ws = (char*)d_ws;
    unsigned int* rankp = (unsigned int*)(ws);
    unsigned long long* kw = (unsigned long long*)(ws + 663552);

    kA<<<163, 1024, 0, stream>>>(cls, rankp, kw);
    kout<<<36, 256, 0, stream>>>(cls, reg, rankp, kw, out);
}

// Round 12
// 81.704 us; speedup vs baseline: 4.0310x; 4.0310x over previous
//
#include <hip/hip_runtime.h>
#include <stdint.h>

#define HH 96
#define WW 96
#define NN (HH*WW)
#define NW 192   // bitmap words: 96 rows x 2 (128-bit padded rows, cols 96..127 dead)

// ws layout (bytes):
//   [0,      663552)  rankp u32[18][9216]  exact stable-rank partials
//   [663552, 665088)  kw    u64[192]       kept bitmap words

__device__ __forceinline__ int coord1(int a) { return (10 * a + 1) / 3; }

// Aligned shifted word: result bit b (cell col 64h+b) = src-row bit (64h+b+dj).
__device__ __forceinline__ unsigned long long shifted(unsigned long long A,
                                                      unsigned long long B,
                                                      int h, int dj) {
    const unsigned long long W0 = h ? B : A;
    if (dj == 0) return W0;
    if (dj > 0) {
        const unsigned long long Wr = h ? 0ULL : B;
        return (W0 >> dj) | (Wr << (64 - dj));
    }
    const int d = -dj;
    const unsigned long long Wl = h ? A : 0ULL;
    return (W0 << d) | (Wl >> (64 - d));
}

// One dispatch, disjoint block roles, ZERO cross-block sync (R6/R8 lesson).
// Blocks 0..161: exact counting-rank partials — bit-compare of non-negative
// floats with index tiebreak IN the partial (R11 post-mortem: the packed
// E/G scheme hit real score-value duplicates — birthday bound ~2.5 pairs in
// 9216 draws — and its per-thread serial rescan fallback cost 325us; exact
// compare here removes the fallback entirely). Block 162: bit-parallel
// greedy NMS (== lexicographically-first MIS; exact-integer iou>0.5 per R0;
// 2nd pass @0.7 provably no-op; geometry constant-folded, R11-validated;
// free-running monotone fixpoint per R10).
__global__ __launch_bounds__(1024, 1) void kA(const float* __restrict__ cls,
                                              unsigned int* __restrict__ rankp,
                                              unsigned long long* __restrict__ kw) {
    __shared__ __align__(16) float s[NN];         // 36 KB (rank blocks use 2 KB)
    __shared__ unsigned long long Hh[12][NW];     // 18 KB
    __shared__ unsigned long long K[NW], D[NW];   // 3 KB
    const int tid = threadIdx.x;
    const int bid = blockIdx.x;

    if (bid < 162) {
        // ---- rank partials: (k-tile of 1024) x (m-half-tile of 512) ----
        // uniform[0,1) scores are non-negative: IEEE bits are order-isomorphic.
        const int kt = bid % 9, mh = bid / 9;
        const int base = mh * 512;
        uint4* smi = (uint4*)s;
        if (tid < 128) smi[tid] = ((const uint4*)(cls + base))[tid];
        __syncthreads();
        const int k = kt * 1024 + tid;
        const unsigned kb = __float_as_uint(cls[k]);
        unsigned cnt = 0;
        #pragma unroll 4
        for (int m4 = 0; m4 < 128; ++m4) {
            const uint4 v = smi[m4];
            const int gm = base + (m4 << 2);
            cnt += (v.x > kb) || (v.x == kb && (gm + 0) < k);
            cnt += (v.y > kb) || (v.y == kb && (gm + 1) < k);
            cnt += (v.z > kb) || (v.z == kb && (gm + 2) < k);
            cnt += (v.w > kb) || (v.w == kb && (gm + 3) < k);
        }
        rankp[mh * NN + k] = cnt;
        return;
    }

    // ---- NMS block ----
    const int lane = tid & 63;
    const int wave = tid >> 6;
    const int offs_di[12] = {0,0, 0,0, -1,1, -2,2, -1,-1, 1,1};
    const int offs_dj[12] = {-1,1,-2,2,  0,0,  0,0, -1, 1,-1,1};
    for (int i = tid; i < NN/4; i += 1024)
        ((float4*)s)[i] = ((const float4*)cls)[i];
    __syncthreads();
    // Build H masks + K/D init via ballot. Word w: row w>>1, col base 64*(w&1);
    // lane l <-> col base+l. 16 waves x 12 iters = 192 words. Geometry folded
    // to (col%3,row%3) patterns (R11-validated, absmax=0).
    for (int it = 0; it < 12; ++it) {
        const int w = wave + (it << 4);
        const int row = w >> 1;
        const int col = ((w & 1) << 6) + lane;
        const bool incell = (col < WW);
        const int c = row * WW + col;
        const float sc = incell ? s[c] : 0.0f;
        const int cm3 = col % 3, rm3 = row % 3;
        const unsigned long long dinit = __ballot(!incell || !(sc > 0.6f));
        if (lane == 0) { D[w] = dinit; K[w] = 0ULL; }
        #pragma unroll
        for (int e = 0; e < 12; ++e) {
            const int ii = row + offs_di[e], jj = col + offs_dj[e];
            bool geo;
            switch (e) {
                case 2:  geo = (cm3 == 1); break;              // (0,-2)
                case 3:  geo = (cm3 == 2); break;              // (0,+2)
                case 6:  geo = (rm3 == 1); break;              // (-2,0)
                case 7:  geo = (rm3 == 2); break;              // (+2,0)
                case 8:  geo = !(cm3 == 2 && rm3 == 2); break; // (-1,-1)
                case 9:  geo = !(cm3 == 1 && rm3 == 2); break; // (-1,+1)
                case 10: geo = !(cm3 == 2 && rm3 == 1); break; // (+1,-1)
                case 11: geo = !(cm3 == 1 && rm3 == 1); break; // (+1,+1)
                default: geo = true;                           // step-1 edges
            }
            bool hp = false;
            if (incell && geo && ii >= 0 && ii < HH && jj >= 0 && jj < WW) {
                const int v = ii * WW + jj;
                const float sv = s[v];
                hp = (sv > sc) || (sv == sc && v < c);
            }
            const unsigned long long m = __ballot(hp);
            if (lane == 0) Hh[e][w] = m;
        }
    }
    __syncthreads();          // last barrier: all 16 waves present
    if (wave >= 3) return;    // waves 3..15 done; 0..2 free-run (no barriers)

    // Free-running monotone fixpoint (R10-validated): thread w owns word w.
    // Write order K-then-D, read order D-then-K: LDS applies per-wave ops in
    // order and volatile preserves program order, so D=1 observed => that
    // neighbor's K is current (no false "determined-not-kept").
    volatile unsigned long long* vK = K;
    volatile unsigned long long* vD = D;
    const int w = tid;
    const int row = w >> 1, h = w & 1;
    unsigned long long Hr[12];
    #pragma unroll
    for (int e = 0; e < 12; ++e) Hr[e] = Hh[e][w];
    unsigned long long myK = K[w], myD = D[w];    // own words: only this thread writes
    for (int iter = 0; iter < 4096; ++iter) {
        if (!~myD) break;                          // fully determined: final
        unsigned long long DA[5], DB[5], KA[5], KB[5];
        #pragma unroll
        for (int q = 0; q < 5; ++q) {              // D reads FIRST
            const int rr = row + q - 2;
            const bool ok = (rr >= 0) && (rr < HH);
            DA[q] = ok ? vD[rr*2]   : 0ULL;
            DB[q] = ok ? vD[rr*2+1] : 0ULL;        // out-of-grid: H=0 there anyway
        }
        #pragma unroll
        for (int q = 0; q < 5; ++q) {              // K reads AFTER D
            const int rr = row + q - 2;
            const bool ok = (rr >= 0) && (rr < HH);
            KA[q] = ok ? vK[rr*2]   : 0ULL;
            KB[q] = ok ? vK[rr*2+1] : 0ULL;
        }
        unsigned long long supp = 0ULL, alldet = ~0ULL;
        #pragma unroll
        for (int e = 0; e < 12; ++e) {
            const int q = offs_di[e] + 2;
            const int dj = offs_dj[e];
            supp   |=  Hr[e] & shifted(KA[q], KB[q], h, dj);
            alldet &= ~Hr[e] | shifted(DA[q], DB[q], h, dj);
        }
        const unsigned long long U = ~myD;
        myK = myK | (U & alldet & ~supp);
        myD = myD | (U & (supp | alldet));
        vK[w] = myK;                               // K write BEFORE D write
        vD[w] = myD;
    }
    kw[w] = myK;   // own word final; no cross-wave read needed
}

// Epilogue: r = rank[k] is a permutation of [0,9216) — every output row
// written exactly once (non-kept rows -> zeros, no d_out memset needed).
__global__ void kout(const float* __restrict__ score, const float* __restrict__ reg,
                     const unsigned int* __restrict__ rankp,
                     const unsigned long long* __restrict__ kw,
                     float* __restrict__ out) {
    const int k = blockIdx.x * 256 + threadIdx.x;
    unsigned r = 0;
    #pragma unroll
    for (int y = 0; y < 18; ++y) r += rankp[y * NN + k];
    const int j = k % WW, i = k / WW;
    const bool kp = ((kw[i * 2 + (j >> 6)] >> (j & 63)) & 1ULL) != 0ULL;
    const float x1 = (float)coord1(j);
    const float y1 = (float)coord1(i);
    const float4 d = ((const float4*)reg)[k];
    float* o = out + (size_t)r * 5;
    o[0] = kp ? (x1 + d.x * 21.0f) : 0.0f;
    o[1] = kp ? (y1 + d.y * 21.0f) : 0.0f;
    o[2] = kp ? (x1 + 20.0f + d.z * 21.0f) : 0.0f;
    o[3] = kp ? (y1 + 20.0f + d.w * 21.0f) : 0.0f;
    o[4] = kp ? score[k] : 0.0f;
}

extern "C" void kernel_launch(void* const* d_in, const int* in_sizes, int n_in,
                              void* d_out, int out_size, void* d_ws, size_t ws_size,
                              hipStream_t stream) {
    const float* cls = (const float*)d_in[0];
    const float* reg = (const float*)d_in[1];
    float* out = (float*)d_out;
    char* ws = (char*)d_ws;
    unsigned int* rankp = (unsigned int*)(ws);
    unsigned long long* kw = (unsigned long long*)(ws + 663552);

    kA<<<163, 1024, 0, stream>>>(cls, rankp, kw);
    kout<<<36, 256, 0, stream>>>(cls, reg, rankp, kw, out);
}